// Round 15
// baseline (34.889 us; speedup 1.0000x reference)
//
#include <hip/hip_runtime.h>

#define BB 16
#define QQ 200
#define NN 200
#define CC 64
#define TT 100
#define GG 50
#define SS 4
#define EE (GG*SS)   // 200

// ws layout: epack [B*E] ints, then cost [B*Q*G] floats
// epack bits: order-original-index o (7b) <<14 | row n (8b) <<6 | class c (6b)

// Kernel B: per-batch stable argsort + edge pack.
__global__ __launch_bounds__(128) void sort_pack_kernel(
    const int* __restrict__ query_indices,    // [B,T]
    const int* __restrict__ target_indices,   // [B,T]
    const int* __restrict__ col_ids,          // [B,E]
    const int* __restrict__ edge_tgt,         // [B,E]
    int* __restrict__ epack)                  // [B,E]
{
    const int b = blockIdx.x;
    const int tid = threadIdx.x;
    __shared__ int tk[TT];
    __shared__ int order_sh[TT];   // sorted pos -> original index

    if (tid < TT) tk[tid] = target_indices[b * TT + tid];
    __syncthreads();
    if (tid < TT) {
        const int key = tk[tid];
        int rank = 0;
        #pragma unroll 4
        for (int j = 0; j < TT; ++j) {
            const int kj = tk[j];
            rank += (kj < key) || (kj == key && j < tid);  // stable
        }
        order_sh[rank] = tid;
    }
    __syncthreads();
    for (int e = tid; e < EE; e += 128) {
        const int t_e = col_ids[b * EE + e];
        const int c_e = edge_tgt[b * EE + e];
        const int o   = order_sh[t_e];                    // original index
        const int n   = query_indices[b * TT + o];        // row id
        epack[b * EE + e] = (o << 14) | (n << 6) | c_e;
    }
}

// Kernel A: persistent stats+gather. 800 blocks, exactly 2 items each
// (item, item+800); item = (b, q-pair). Pure streaming stats (static
// bounds, loads issue immediately), L1-hot gather, writes cost[b][q][g].
__global__ __launch_bounds__(256) void stats_gather_kernel(
    const float* __restrict__ edges,          // [B,Q,N,C]
    const int* __restrict__ query_indices,    // [B,T]
    const int* __restrict__ epack,            // [B,E] (ws, from B)
    float* __restrict__ cost)                 // [B,Q,G] (ws)
{
    const int tid = threadIdx.x;
    const int grp  = tid >> 4;
    const int lane = tid & 15;

    __shared__ int   ep_sh[EE];
    __shared__ float sm_sh[2][TT];

    #pragma unroll
    for (int rep = 0; rep < 2; ++rep) {
        const int item = blockIdx.x + rep * 800;   // 0..1599
        const int b  = item / (QQ / 2);
        const int q0 = (item % (QQ / 2)) * 2;

        if (tid < EE) ep_sh[tid] = epack[b * EE + tid];

        const float* base = edges + ((size_t)(b * QQ + q0)) * NN * CC;
        const int* qi_g = query_indices + b * TT;

        // Stats: sum-exp per original t, both slabs; static trip count,
        // full unroll -> all loads pipelined from kernel entry.
        #pragma unroll
        for (int it = 0; it < 7; ++it) {
            const int t = grp + it * 16;
            if (t < TT) {
                const int n = qi_g[t];
                const float* r0 = base + (size_t)n * CC;
                const float4 v0 = reinterpret_cast<const float4*>(r0)[lane];
                const float4 v1 = reinterpret_cast<const float4*>(r0 + NN * CC)[lane];
                float e0 = __expf(v0.x) + __expf(v0.y) + __expf(v0.z) + __expf(v0.w);
                float e1 = __expf(v1.x) + __expf(v1.y) + __expf(v1.z) + __expf(v1.w);
                #pragma unroll
                for (int off = 1; off < 16; off <<= 1) {
                    e0 += __shfl_xor(e0, off, 64);
                    e1 += __shfl_xor(e1, off, 64);
                }
                if (lane == 0) { sm_sh[0][t] = e0; sm_sh[1][t] = e1; }
            }
        }
        __syncthreads();   // sm_sh + ep_sh ready

        // Gather: per-edge prob (slab L1/L2-hot), group-of-4 reduce.
        if (tid < EE) {
            const int pk = ep_sh[tid];
            const int o = pk >> 14;
            const int n = (pk >> 6) & 255;
            const int c = pk & 63;
            const size_t roff = (size_t)n * CC + c;
            float p0 = __expf(base[roff]) / sm_sh[0][o];
            float p1 = __expf(base[(size_t)NN * CC + roff]) / sm_sh[1][o];
            p0 += __shfl_xor(p0, 1, 64);  p1 += __shfl_xor(p1, 1, 64);
            p0 += __shfl_xor(p0, 2, 64);  p1 += __shfl_xor(p1, 2, 64);
            if ((tid & 3) == 0) {
                cost[((size_t)b * QQ + q0)     * GG + (tid >> 2)] = -p0;
                cost[((size_t)b * QQ + q0 + 1) * GG + (tid >> 2)] = -p1;
            }
        }
        __syncthreads();   // protect sm_sh/ep_sh before next item
    }
}

// Kernel C: replicate cat[q, j] = cost[j/G][q][j%G] to all 16 batch copies.
__global__ __launch_bounds__(256) void replicate_kernel(
    const float* __restrict__ cost,           // [B,Q,G] (ws)
    float* __restrict__ out)                  // [B,Q,B*G]
{
    int i = blockIdx.x * 256 + threadIdx.x;
    if (i < QQ * BB * GG) {
        const int q = i / (BB * GG);
        const int j = i % (BB * GG);
        const int bsrc = j / GG;
        const int g    = j % GG;
        const float v = cost[((size_t)bsrc * QQ + q) * GG + g];
        #pragma unroll
        for (int b2 = 0; b2 < BB; ++b2)
            out[((size_t)b2 * QQ + q) * (BB * GG) + j] = v;
    }
}

extern "C" void kernel_launch(void* const* d_in, const int* in_sizes, int n_in,
                              void* d_out, int out_size, void* d_ws, size_t ws_size,
                              hipStream_t stream) {
    const float* edges = (const float*)d_in[0];          // [B,Q,N,C] f32
    const int* query_indices  = (const int*)d_in[1];     // [B,T]
    const int* target_indices = (const int*)d_in[2];     // [B,T]
    const int* col_ids        = (const int*)d_in[3];     // [B,G,S]
    const int* edge_tgt       = (const int*)d_in[4];     // [B,G,S]
    float* out = (float*)d_out;                          // [B,Q,B*G]

    int*   epack = (int*)d_ws;                           // B*E ints
    float* cost  = (float*)((char*)d_ws + BB * EE * sizeof(int));  // B*Q*G floats

    sort_pack_kernel<<<BB, 128, 0, stream>>>(query_indices, target_indices,
                                             col_ids, edge_tgt, epack);
    stats_gather_kernel<<<800, 256, 0, stream>>>(edges, query_indices, epack, cost);
    replicate_kernel<<<(QQ * BB * GG + 255) / 256, 256, 0, stream>>>(cost, out);
}

// Round 16
// 29.780 us; speedup vs baseline: 1.1716x; 1.1716x over previous
//
#include <hip/hip_runtime.h>

#define BB 16
#define QQ 200
#define NN 200
#define CC 64
#define TT 100
#define GG 50
#define SS 4
#define EE (GG*SS)   // 200

// ws layout: rowlist [B*T] ints (row ids sorted ascending, duplicates kept),
//            epack   [B*E] ints = slot(7b)<<14 | n(8b)<<6 | class(6b)

// Prep kernel (independent, 16 blocks): both rank-sorts fused in one loop;
// emits rowlist (ascending row order for the stats sweep) and fully
// pre-resolved per-edge packs. Launch-pipelined => free (R1 evidence).
__global__ __launch_bounds__(128) void prep_kernel(
    const int* __restrict__ query_indices,    // [B,T]
    const int* __restrict__ target_indices,   // [B,T]
    const int* __restrict__ col_ids,          // [B,E]
    const int* __restrict__ edge_tgt,         // [B,E]
    int* __restrict__ rowlist,                // [B,T] ws
    int* __restrict__ epack)                  // [B,E] ws
{
    const int b = blockIdx.x;
    const int tid = threadIdx.x;
    __shared__ int tk[TT], qi[TT];
    __shared__ int order_sh[TT];   // sorted-by-target pos -> original t
    __shared__ int slotq[TT];      // original t -> ascending-row slot

    if (tid < TT) {
        tk[tid] = target_indices[b * TT + tid];
        qi[tid] = query_indices[b * TT + tid];
    }
    __syncthreads();
    if (tid < TT) {
        const int kt = tk[tid], kq = qi[tid];
        int rT = 0, rQ = 0;
        #pragma unroll 4
        for (int j = 0; j < TT; ++j) {
            const int tj = tk[j], qj = qi[j];
            rT += (tj < kt) || (tj == kt && j < tid);   // stable argsort (target)
            rQ += (qj < kq) || (qj == kq && j < tid);   // stable sort by row id
        }
        order_sh[rT] = tid;
        slotq[tid] = rQ;
        rowlist[b * TT + rQ] = kq;
    }
    __syncthreads();
    for (int e = tid; e < EE; e += 128) {
        const int t_e = col_ids[b * EE + e];
        const int c_e = edge_tgt[b * EE + e];
        const int o   = order_sh[t_e];    // original t after target-sort
        epack[b * EE + e] = (slotq[o] << 14) | (qi[o] << 6) | c_e;
    }
}

// Main kernel: 1600 blocks (b, q-pair). No sorts, no pre-stats barrier.
// Stats sweeps rows in ASCENDING address order (rowlist), static 7-iter
// unroll, loads issue from cycle ~0; sm indexed by slot; gather via epack;
// group-of-4 sum; broadcast write (R12-proven structure).
__global__ __launch_bounds__(256) void stats_gather_kernel(
    const float* __restrict__ edges,          // [B,Q,N,C]
    const int* __restrict__ rowlist,          // [B,T] ws
    const int* __restrict__ epack,            // [B,E] ws
    float* __restrict__ out)                  // [B,Q,B*G]
{
    const int blk = blockIdx.x;
    const int b  = blk / (QQ / 2);
    const int q0 = (blk % (QQ / 2)) * 2;
    const int tid = threadIdx.x;
    const int grp  = tid >> 4;
    const int lane = tid & 15;

    __shared__ int   ep_sh[EE];
    __shared__ float sm_sh[2][TT];     // indexed by ascending-row slot
    __shared__ float cost_sh[2][GG];

    if (tid < EE) ep_sh[tid] = epack[b * EE + tid];   // consumed after barrier

    const float* base = edges + ((size_t)(b * QQ + q0)) * NN * CC;
    const int* rl = rowlist + b * TT;

    // Stats: ascending-address sweep; group-uniform L2-hot index loads;
    // static trip count -> full unroll, all row loads pipelined.
    #pragma unroll
    for (int it = 0; it < 7; ++it) {
        const int t = grp + it * 16;
        if (t < TT) {
            const int n = rl[t];
            const float* r0 = base + (size_t)n * CC;
            const float4 v0 = reinterpret_cast<const float4*>(r0)[lane];
            const float4 v1 = reinterpret_cast<const float4*>(r0 + NN * CC)[lane];
            float e0 = __expf(v0.x) + __expf(v0.y) + __expf(v0.z) + __expf(v0.w);
            float e1 = __expf(v1.x) + __expf(v1.y) + __expf(v1.z) + __expf(v1.w);
            #pragma unroll
            for (int off = 1; off < 16; off <<= 1) {
                e0 += __shfl_xor(e0, off, 64);
                e1 += __shfl_xor(e1, off, 64);
            }
            if (lane == 0) { sm_sh[0][t] = e0; sm_sh[1][t] = e1; }
        }
    }
    __syncthreads();

    // Gather: per-edge probability for both q's, group-of-4 reduce.
    if (tid < EE) {
        const int pk = ep_sh[tid];
        const int slot = pk >> 14;
        const int n    = (pk >> 6) & 255;
        const int c    = pk & 63;
        const size_t roff = (size_t)n * CC + c;
        float p0 = __expf(base[roff]) / sm_sh[0][slot];
        float p1 = __expf(base[(size_t)NN * CC + roff]) / sm_sh[1][slot];
        p0 += __shfl_xor(p0, 1, 64);  p1 += __shfl_xor(p1, 1, 64);
        p0 += __shfl_xor(p0, 2, 64);  p1 += __shfl_xor(p1, 2, 64);
        if ((tid & 3) == 0) {
            cost_sh[0][tid >> 2] = -p0;
            cost_sh[1][tid >> 2] = -p1;
        }
    }
    __syncthreads();

    // Broadcast write: out[b2, q0+qq, b*G+g] for all b2, both q's.
    for (int i = tid; i < 2 * BB * GG; i += 256) {
        const int qq = i / (BB * GG);
        const int r  = i % (BB * GG);
        const int b2 = r / GG;
        const int g  = r % GG;
        out[((size_t)b2 * QQ + q0 + qq) * (BB * GG) + b * GG + g] = cost_sh[qq][g];
    }
}

extern "C" void kernel_launch(void* const* d_in, const int* in_sizes, int n_in,
                              void* d_out, int out_size, void* d_ws, size_t ws_size,
                              hipStream_t stream) {
    const float* edges = (const float*)d_in[0];          // [B,Q,N,C] f32
    const int* query_indices  = (const int*)d_in[1];     // [B,T]
    const int* target_indices = (const int*)d_in[2];     // [B,T]
    const int* col_ids        = (const int*)d_in[3];     // [B,G,S]
    const int* edge_tgt       = (const int*)d_in[4];     // [B,G,S]
    float* out = (float*)d_out;                          // [B,Q,B*G]

    int* rowlist = (int*)d_ws;                           // B*T ints
    int* epack   = rowlist + BB * TT;                    // B*E ints

    prep_kernel<<<BB, 128, 0, stream>>>(query_indices, target_indices,
                                        col_ids, edge_tgt, rowlist, epack);
    stats_gather_kernel<<<BB * (QQ / 2), 256, 0, stream>>>(edges, rowlist,
                                                           epack, out);
}

// Round 17
// 27.508 us; speedup vs baseline: 1.2683x; 1.0826x over previous
//
#include <hip/hip_runtime.h>

#define BB 16
#define QQ 200
#define NN 200
#define CC 64
#define TT 100
#define GG 50
#define SS 4
#define EE (GG*SS)   // 200

// Main kernel (R14 structure, writes dense cost only):
//  - stats: sum-exp per ORIGINAL t (row qi[t] direct from global), loads
//    issue from kernel entry, static 7-iter unroll, QPB=2.
//  - sort: rank-inversion overlapped behind in-flight stats loads.
//  - gather: per-edge prob, group-of-4 reduce, DIRECT store of 100 floats
//    (contiguous 400B per block) to cost[b][q][g]. No LDS staging/barrier.
__global__ __launch_bounds__(256) void stats_gather_kernel(
    const float* __restrict__ edges,          // [B,Q,N,C]
    const int* __restrict__ query_indices,    // [B,T]
    const int* __restrict__ target_indices,   // [B,T]
    const int* __restrict__ col_ids,          // [B,E]
    const int* __restrict__ edge_tgt,         // [B,E]
    float* __restrict__ cost)                 // [B,Q,G] ws
{
    const int blk = blockIdx.x;
    const int b  = blk / (QQ / 2);
    const int q0 = (blk % (QQ / 2)) * 2;
    const int tid = threadIdx.x;
    const int grp  = tid >> 4;
    const int lane = tid & 15;

    __shared__ int   tk[TT];
    __shared__ int   qi[TT];
    __shared__ int   order_sh[TT];       // sorted pos -> original index
    __shared__ int   ep_sh[EE];          // t*64 + class packed
    __shared__ float sm_sh[2][TT];       // sum-exp indexed by ORIGINAL t

    if (tid < TT) {
        tk[tid] = target_indices[b * TT + tid];
        qi[tid] = query_indices[b * TT + tid];
    }
    if (tid < EE) {
        const int t_e = col_ids[b * EE + tid];
        const int c_e = edge_tgt[b * EE + tid];
        ep_sh[tid] = t_e * 64 + c_e;
    }

    const float* base = edges + ((size_t)(b * QQ + q0)) * NN * CC;
    const int* qi_g = query_indices + b * TT;

    // Stats: static trip count -> full unroll, all row loads pipelined.
    #pragma unroll
    for (int it = 0; it < 7; ++it) {
        const int t = grp + it * 16;
        if (t < TT) {
            const int n = qi_g[t];
            const float* r0 = base + (size_t)n * CC;
            const float4 v0 = reinterpret_cast<const float4*>(r0)[lane];
            const float4 v1 = reinterpret_cast<const float4*>(r0 + NN * CC)[lane];
            float e0 = __expf(v0.x) + __expf(v0.y) + __expf(v0.z) + __expf(v0.w);
            float e1 = __expf(v1.x) + __expf(v1.y) + __expf(v1.z) + __expf(v1.w);
            #pragma unroll
            for (int off = 1; off < 16; off <<= 1) {
                e0 += __shfl_xor(e0, off, 64);
                e1 += __shfl_xor(e1, off, 64);
            }
            if (lane == 0) { sm_sh[0][t] = e0; sm_sh[1][t] = e1; }
        }
    }
    __syncthreads();   // covers staging AND sm_sh

    // Stable argsort rank inversion (overlapped with stats loads above).
    if (tid < TT) {
        const int key = tk[tid];
        int rank = 0;
        #pragma unroll 4
        for (int j = 0; j < TT; ++j) {
            const int kj = tk[j];
            rank += (kj < key) || (kj == key && j < tid);
        }
        order_sh[rank] = tid;
    }
    __syncthreads();

    // Gather + direct dense store (no LDS staging, no final barrier).
    if (tid < EE) {
        const int pack = ep_sh[tid];
        const int t_e = pack >> 6;
        const int c   = pack & 63;
        const int o   = order_sh[t_e];
        const size_t roff = (size_t)qi[o] * CC + c;
        float p0 = __expf(base[roff]) / sm_sh[0][o];
        float p1 = __expf(base[(size_t)NN * CC + roff]) / sm_sh[1][o];
        p0 += __shfl_xor(p0, 1, 64);  p1 += __shfl_xor(p1, 1, 64);
        p0 += __shfl_xor(p0, 2, 64);  p1 += __shfl_xor(p1, 2, 64);
        if ((tid & 3) == 0) {
            const int g = tid >> 2;
            cost[((size_t)b * QQ + q0)     * GG + g] = -p0;
            cost[((size_t)b * QQ + q0 + 1) * GG + g] = -p1;
        }
    }
}

// Replicate kernel (validated in R15): cat[q,j] = cost[j/G][q][j%G],
// broadcast to all 16 batch copies with coalesced wave-stores.
__global__ __launch_bounds__(256) void replicate_kernel(
    const float* __restrict__ cost,           // [B,Q,G] ws
    float* __restrict__ out)                  // [B,Q,B*G]
{
    int i = blockIdx.x * 256 + threadIdx.x;
    if (i < QQ * BB * GG) {
        const int q = i / (BB * GG);
        const int j = i % (BB * GG);
        const int bsrc = j / GG;
        const int g    = j % GG;
        const float v = cost[((size_t)bsrc * QQ + q) * GG + g];
        #pragma unroll
        for (int b2 = 0; b2 < BB; ++b2)
            out[((size_t)b2 * QQ + q) * (BB * GG) + j] = v;
    }
}

extern "C" void kernel_launch(void* const* d_in, const int* in_sizes, int n_in,
                              void* d_out, int out_size, void* d_ws, size_t ws_size,
                              hipStream_t stream) {
    const float* edges = (const float*)d_in[0];          // [B,Q,N,C] f32
    const int* query_indices  = (const int*)d_in[1];     // [B,T]
    const int* target_indices = (const int*)d_in[2];     // [B,T]
    const int* col_ids        = (const int*)d_in[3];     // [B,G,S]
    const int* edge_tgt       = (const int*)d_in[4];     // [B,G,S]
    float* out = (float*)d_out;                          // [B,Q,B*G]

    float* cost = (float*)d_ws;                          // B*Q*G floats

    stats_gather_kernel<<<BB * (QQ / 2), 256, 0, stream>>>(
        edges, query_indices, target_indices, col_ids, edge_tgt, cost);
    replicate_kernel<<<(QQ * BB * GG + 255) / 256, 256, 0, stream>>>(cost, out);
}

// Round 18
// 26.588 us; speedup vs baseline: 1.3122x; 1.0346x over previous
//
#include <hip/hip_runtime.h>

#define BB 16
#define QQ 200
#define NN 200
#define CC 64
#define TT 100
#define GG 50
#define SS 4
#define EE (GG*SS)   // 200
#define QPB 4        // q's per block; all loop bounds compile-time

// Fused kernel, QPB=4 (R14 skeleton):
//  - stats: sum-exp per ORIGINAL t (row qi[t] direct from global), loads
//    issue from kernel entry, static 7-iter unroll, 4 slabs per index.
//  - sort: rank-inversion overlapped behind in-flight stats loads.
//  - gather: per-edge prob x4, group-of-4 reduce, LDS stage.
//  - broadcast write for 4 q-rows.
__global__ __launch_bounds__(256) void edge_cost_fused_kernel(
    const float* __restrict__ edges,          // [B,Q,N,C]
    const int* __restrict__ query_indices,    // [B,T]
    const int* __restrict__ target_indices,   // [B,T]
    const int* __restrict__ col_ids,          // [B,E]
    const int* __restrict__ edge_tgt,         // [B,E]
    float* __restrict__ out)                  // [B,Q,B*G]
{
    const int blk = blockIdx.x;
    const int b  = blk / (QQ / QPB);
    const int q0 = (blk % (QQ / QPB)) * QPB;
    const int tid = threadIdx.x;
    const int grp  = tid >> 4;
    const int lane = tid & 15;

    __shared__ int   tk[TT];
    __shared__ int   qi[TT];
    __shared__ int   order_sh[TT];       // sorted pos -> original index
    __shared__ int   ep_sh[EE];          // t*64 + class packed
    __shared__ float sm_sh[QPB][TT];     // sum-exp indexed by ORIGINAL t
    __shared__ float cost_sh[QPB][GG];

    if (tid < TT) {
        tk[tid] = target_indices[b * TT + tid];
        qi[tid] = query_indices[b * TT + tid];
    }
    if (tid < EE) {
        const int t_e = col_ids[b * EE + tid];
        const int c_e = edge_tgt[b * EE + tid];
        ep_sh[tid] = t_e * 64 + c_e;
    }

    const float* base = edges + ((size_t)(b * QQ + q0)) * NN * CC;
    const int* qi_g = query_indices + b * TT;

    // Stats: static trip count -> full unroll; 4 slabs per row index.
    // All array indices are compile-time after unroll (no scratch).
    #pragma unroll
    for (int it = 0; it < 7; ++it) {
        const int t = grp + it * 16;
        if (t < TT) {
            const int n = qi_g[t];
            const float* r0 = base + (size_t)n * CC;
            float e[QPB];
            #pragma unroll
            for (int qq = 0; qq < QPB; ++qq) {
                const float4 v = reinterpret_cast<const float4*>(
                    r0 + (size_t)qq * NN * CC)[lane];
                e[qq] = __expf(v.x) + __expf(v.y) + __expf(v.z) + __expf(v.w);
            }
            #pragma unroll
            for (int off = 1; off < 16; off <<= 1) {
                #pragma unroll
                for (int qq = 0; qq < QPB; ++qq)
                    e[qq] += __shfl_xor(e[qq], off, 64);
            }
            if (lane == 0) {
                #pragma unroll
                for (int qq = 0; qq < QPB; ++qq) sm_sh[qq][t] = e[qq];
            }
        }
    }
    __syncthreads();   // covers tk/qi/ep staging AND sm_sh writes

    // Stable argsort rank inversion (overlapped with stats loads above).
    if (tid < TT) {
        const int key = tk[tid];
        int rank = 0;
        #pragma unroll 4
        for (int j = 0; j < TT; ++j) {
            const int kj = tk[j];
            rank += (kj < key) || (kj == key && j < tid);
        }
        order_sh[rank] = tid;
    }
    __syncthreads();

    // Gather: per-edge probability x4, group-of-4 reduce.
    if (tid < EE) {
        const int pack = ep_sh[tid];
        const int t_e = pack >> 6;
        const int c   = pack & 63;
        const int o   = order_sh[t_e];
        const size_t roff = (size_t)qi[o] * CC + c;
        float p[QPB];
        #pragma unroll
        for (int qq = 0; qq < QPB; ++qq)
            p[qq] = __expf(base[(size_t)qq * NN * CC + roff]) / sm_sh[qq][o];
        #pragma unroll
        for (int qq = 0; qq < QPB; ++qq) {
            p[qq] += __shfl_xor(p[qq], 1, 64);
            p[qq] += __shfl_xor(p[qq], 2, 64);
        }
        if ((tid & 3) == 0) {
            const int g = tid >> 2;
            #pragma unroll
            for (int qq = 0; qq < QPB; ++qq) cost_sh[qq][g] = -p[qq];
        }
    }
    __syncthreads();

    // Broadcast write: out[b2, q0+qq, b*G+g] for all b2, 4 q's.
    for (int i = tid; i < QPB * BB * GG; i += 256) {
        const int qq = i / (BB * GG);
        const int r  = i % (BB * GG);
        const int b2 = r / GG;
        const int g  = r % GG;
        out[((size_t)b2 * QQ + q0 + qq) * (BB * GG) + b * GG + g] = cost_sh[qq][g];
    }
}

extern "C" void kernel_launch(void* const* d_in, const int* in_sizes, int n_in,
                              void* d_out, int out_size, void* d_ws, size_t ws_size,
                              hipStream_t stream) {
    const float* edges = (const float*)d_in[0];          // [B,Q,N,C] f32
    const int* query_indices  = (const int*)d_in[1];     // [B,T]
    const int* target_indices = (const int*)d_in[2];     // [B,T]
    const int* col_ids        = (const int*)d_in[3];     // [B,G,S]
    const int* edge_tgt       = (const int*)d_in[4];     // [B,G,S]
    float* out = (float*)d_out;                          // [B,Q,B*G]

    edge_cost_fused_kernel<<<BB * (QQ / QPB), 256, 0, stream>>>(
        edges, query_indices, target_indices, col_ids, edge_tgt, out);
}

// Round 19
// 26.050 us; speedup vs baseline: 1.3393x; 1.0207x over previous
//
#include <hip/hip_runtime.h>

#define BB 16
#define QQ 200
#define NN 200
#define CC 64
#define TT 100
#define GG 50
#define SS 4
#define EE (GG*SS)   // 200
#define QPB 2        // q's per block (measured optimum)

// Fused kernel, QPB=2, ONE pre-gather barrier:
//  - stats: sum-exp per ORIGINAL t (row qi[t] direct from global), static
//    7-iter unroll, loads issue from kernel entry.
//  - sort: rank loop reads target_indices DIRECT from global (lane-uniform
//    j -> scalar loads) — depends on NO LDS, runs inside the stats-load
//    latency shadow. order_sh[rank]=tid.
//  - single barrier covers {sm_sh, order_sh, qi_sh, ep_sh}; then gather,
//    group-of-4 reduce, LDS cost stage, broadcast write.
__global__ __launch_bounds__(256) void edge_cost_fused_kernel(
    const float* __restrict__ edges,          // [B,Q,N,C]
    const int* __restrict__ query_indices,    // [B,T]
    const int* __restrict__ target_indices,   // [B,T]
    const int* __restrict__ col_ids,          // [B,E]
    const int* __restrict__ edge_tgt,         // [B,E]
    float* __restrict__ out)                  // [B,Q,B*G]
{
    const int blk = blockIdx.x;
    const int b  = blk / (QQ / QPB);
    const int q0 = (blk % (QQ / QPB)) * QPB;
    const int tid = threadIdx.x;
    const int grp  = tid >> 4;
    const int lane = tid & 15;

    __shared__ int   qi_sh[TT];
    __shared__ int   order_sh[TT];       // sorted pos -> original index
    __shared__ int   ep_sh[EE];          // t*64 + class packed
    __shared__ float sm_sh[QPB][TT];     // sum-exp indexed by ORIGINAL t
    __shared__ float cost_sh[QPB][GG];

    const float* base = edges + ((size_t)(b * QQ + q0)) * NN * CC;
    const int* qi_g = query_indices + b * TT;
    const int* tk_g = target_indices + b * TT;

    // Staging (no consumer before the single barrier).
    if (tid < TT) qi_sh[tid] = qi_g[tid];
    if (tid < EE) {
        const int t_e = col_ids[b * EE + tid];
        const int c_e = edge_tgt[b * EE + tid];
        ep_sh[tid] = t_e * 64 + c_e;
    }

    // Stats: static trip count -> full unroll, all row loads pipelined.
    #pragma unroll
    for (int it = 0; it < 7; ++it) {
        const int t = grp + it * 16;
        if (t < TT) {
            const int n = qi_g[t];
            const float* r0 = base + (size_t)n * CC;
            const float4 v0 = reinterpret_cast<const float4*>(r0)[lane];
            const float4 v1 = reinterpret_cast<const float4*>(r0 + NN * CC)[lane];
            float e0 = __expf(v0.x) + __expf(v0.y) + __expf(v0.z) + __expf(v0.w);
            float e1 = __expf(v1.x) + __expf(v1.y) + __expf(v1.z) + __expf(v1.w);
            #pragma unroll
            for (int off = 1; off < 16; off <<= 1) {
                e0 += __shfl_xor(e0, off, 64);
                e1 += __shfl_xor(e1, off, 64);
            }
            if (lane == 0) { sm_sh[0][t] = e0; sm_sh[1][t] = e1; }
        }
    }

    // Sort: rank loop on GLOBAL keys (lane-uniform j -> scalar loads),
    // independent of LDS and of the stats loads above.
    if (tid < TT) {
        const int key = tk_g[tid];
        int rank = 0;
        #pragma unroll 4
        for (int j = 0; j < TT; ++j) {
            const int kj = tk_g[j];
            rank += (kj < key) || (kj == key && j < tid);
        }
        order_sh[rank] = tid;
    }
    __syncthreads();   // single barrier: sm_sh, order_sh, qi_sh, ep_sh

    // Gather: per-edge probability for both q's, group-of-4 reduce.
    if (tid < EE) {
        const int pack = ep_sh[tid];
        const int t_e = pack >> 6;
        const int c   = pack & 63;
        const int o   = order_sh[t_e];
        const size_t roff = (size_t)qi_sh[o] * CC + c;
        float p0 = __expf(base[roff]) / sm_sh[0][o];
        float p1 = __expf(base[(size_t)NN * CC + roff]) / sm_sh[1][o];
        p0 += __shfl_xor(p0, 1, 64);  p1 += __shfl_xor(p1, 1, 64);
        p0 += __shfl_xor(p0, 2, 64);  p1 += __shfl_xor(p1, 2, 64);
        if ((tid & 3) == 0) {
            cost_sh[0][tid >> 2] = -p0;
            cost_sh[1][tid >> 2] = -p1;
        }
    }
    __syncthreads();

    // Broadcast write: out[b2, q0+qq, b*G+g] for all b2, both q's.
    for (int i = tid; i < QPB * BB * GG; i += 256) {
        const int qq = i / (BB * GG);
        const int r  = i % (BB * GG);
        const int b2 = r / GG;
        const int g  = r % GG;
        out[((size_t)b2 * QQ + q0 + qq) * (BB * GG) + b * GG + g] = cost_sh[qq][g];
    }
}

extern "C" void kernel_launch(void* const* d_in, const int* in_sizes, int n_in,
                              void* d_out, int out_size, void* d_ws, size_t ws_size,
                              hipStream_t stream) {
    const float* edges = (const float*)d_in[0];          // [B,Q,N,C] f32
    const int* query_indices  = (const int*)d_in[1];     // [B,T]
    const int* target_indices = (const int*)d_in[2];     // [B,T]
    const int* col_ids        = (const int*)d_in[3];     // [B,G,S]
    const int* edge_tgt       = (const int*)d_in[4];     // [B,G,S]
    float* out = (float*)d_out;                          // [B,Q,B*G]

    edge_cost_fused_kernel<<<BB * (QQ / QPB), 256, 0, stream>>>(
        edges, query_indices, target_indices, col_ids, edge_tgt, out);
}